// Round 5
// baseline (294.062 us; speedup 1.0000x reference)
//
#include <hip/hip_runtime.h>
#include <hip/hip_bf16.h>
#include <math.h>

#define N_NODES 50000
#define N_EDGES 400000
#define F_IN    64
#define HID     128
#define FIN     192   /* F_IN + HID */
#define RU      256   /* 2*HID */

#define NSCAN   196   /* ceil(N_NODES/256) */

/* ---- ws layout (byte offsets), total ~33.2 MB ----
   rs     : int[N_NODES]          @ RS_OFF   CSR starts (mutated to ends by fill)
   csr    : ushort[N_EDGES]       @ CSR_OFF
   bsum   : int[256]              @ BSUM_OFF
   Wru_bf : bf16[RU][FIN]         @ WRU_OFF  (transposed W_ru)
   Wc_bf  : bf16[HID][FIN]        @ WC_OFF   (transposed W_c)
   s_bf   : bf16[N][HID]          @ SBF_OFF  [prep,agg1]; counts[] aliased pre-prep;
                                             A_rs aliased after agg1 (written by agg2)
   Ax     : bf16[N][F_IN]         @ AX_OFF   [agg1, gemm_c]
   As     : bf16[N][HID]          @ AS_OFF   [agg1, gemm_ru]; rs_bf aliased in-place
                                             (gemm_ru overwrites its own rows post-barrier)
   x_bf   : bf16[N][F_IN]  lives in d_out[0:6.4MB] (dead before gemm_c writes out1) */
#define RS_OFF    0u
#define CSR_OFF   200064u
#define BSUM_OFF  1000064u
#define WRU_OFF   1001088u
#define WC_OFF    1099392u
#define SBF_OFF   1148544u
#define AX_OFF    13948544u
#define AS_OFF    20348544u

typedef __attribute__((ext_vector_type(8))) short short8;
typedef __attribute__((ext_vector_type(4))) float f32x4;

__device__ __forceinline__ float sigf(float x) { return 1.f / (1.f + expf(-x)); }
__device__ __forceinline__ float bf2f(unsigned short h) {
    return __uint_as_float(((unsigned)h) << 16);
}
__device__ __forceinline__ unsigned short f2bf(float f) { /* RNE */
    unsigned u = __float_as_uint(f);
    return (unsigned short)((u + 0x7fff + ((u >> 16) & 1)) >> 16);
}
__device__ __forceinline__ unsigned packbf(float lo, float hi) {
    return ((unsigned)f2bf(hi) << 16) | (unsigned)f2bf(lo);
}

/* ---------------- CSR build ---------------- */
__global__ void k_hist(const int* __restrict__ dst, int* __restrict__ counts) {
    const int e = blockIdx.x * 256 + threadIdx.x;
    if (e < N_EDGES) atomicAdd(&counts[dst[e]], 1);
}

__device__ __forceinline__ int excl_scan_256(int v, int* tmp) {
    const int t = threadIdx.x;
    tmp[t] = v; __syncthreads();
    #pragma unroll
    for (int off = 1; off < 256; off <<= 1) {
        int u = (t >= off) ? tmp[t - off] : 0;
        __syncthreads();
        tmp[t] += u;
        __syncthreads();
    }
    return tmp[t] - v;
}

__global__ void k_scan_a(const int* __restrict__ counts, int* __restrict__ bsum) {
    __shared__ int tmp[256];
    const int i = blockIdx.x * 256 + threadIdx.x;
    const int v = (i < N_NODES) ? counts[i] : 0;
    excl_scan_256(v, tmp);
    if (threadIdx.x == 255) bsum[blockIdx.x] = tmp[255];
}

__global__ void k_scan_b(int* __restrict__ bsum) {
    __shared__ int tmp[256];
    const int t = threadIdx.x;
    const int v = (t < NSCAN) ? bsum[t] : 0;
    const int e = excl_scan_256(v, tmp);
    bsum[t] = e;
}

__global__ void k_scan_c(const int* __restrict__ counts, const int* __restrict__ bsum,
                         int* __restrict__ rs) {
    __shared__ int tmp[256];
    const int i = blockIdx.x * 256 + threadIdx.x;
    const int v = (i < N_NODES) ? counts[i] : 0;
    const int e = excl_scan_256(v, tmp);
    if (i < N_NODES) rs[i] = bsum[blockIdx.x] + e;
}

__global__ void k_fill(const int* __restrict__ src, const int* __restrict__ dst,
                       int* __restrict__ rs, unsigned short* __restrict__ csr) {
    const int e = blockIdx.x * 256 + threadIdx.x;
    if (e < N_EDGES) {
        const int pos = atomicAdd(&rs[dst[e]], 1);
        csr[pos] = (unsigned short)src[e];
    }
}

/* ------- prepW: transpose W to [col][k] and convert f32->bf16 (reads coalesced) --- */
__global__ void k_prepW(const float* __restrict__ Wru, const float* __restrict__ Wc,
                        unsigned short* __restrict__ Wru_bf,
                        unsigned short* __restrict__ Wc_bf) {
    const int t = blockIdx.x * 256 + threadIdx.x;   /* 73728 threads exact */
    if (t < FIN * RU) {
        const int k = t >> 8, c = t & 255;
        Wru_bf[c * FIN + k] = f2bf(Wru[t]);
    } else {
        const int tt = t - FIN * RU;
        const int k = tt >> 7, c = tt & 127;
        Wc_bf[c * FIN + k] = f2bf(Wc[tt]);
    }
}

/* ------- prep: states -> s_bf, inputs -> x_bf (bf16 gather tables) ------- */
__global__ void k_prep(const float* __restrict__ states, const float* __restrict__ inputs,
                       uint2* __restrict__ s_bf2, uint2* __restrict__ x_bf2) {
    const int t = blockIdx.x * 256 + threadIdx.x;   /* 2.4M threads exact */
    if (t < N_NODES * HID / 4) {
        const float4 v = ((const float4*)states)[t];
        s_bf2[t] = make_uint2(packbf(v.x, v.y), packbf(v.z, v.w));
    } else {
        const int j = t - N_NODES * HID / 4;
        const float4 v = ((const float4*)inputs)[j];
        x_bf2[j] = make_uint2(packbf(v.x, v.y), packbf(v.z, v.w));
    }
}

/* ------- agg1: wave/node; gather x_bf,s_bf; normalize; write Ax,As (bf16) ------- */
__global__ __launch_bounds__(256) void k_agg1(
        const unsigned short* __restrict__ csr, const int* __restrict__ rs,
        const unsigned short* __restrict__ x_bf, const unsigned* __restrict__ s_bfu,
        unsigned short* __restrict__ Ax, unsigned* __restrict__ As_u) {
    const int n = blockIdx.x * 4 + (threadIdx.x >> 6);
    const int lane  = threadIdx.x & 63;
    const int end   = rs[n];
    const int start = n ? rs[n - 1] : 0;
    float ax = 0.f, s0 = 0.f, s1 = 0.f;
    for (int e = start; e < end; ++e) {
        const int se = csr[e];
        ax += bf2f(x_bf[(size_t)se * F_IN + lane]);
        const unsigned sv = s_bfu[(size_t)se * 64 + lane];
        s0 += bf2f((unsigned short)(sv & 0xffffu));
        s1 += bf2f((unsigned short)(sv >> 16));
    }
    const float inv = 1.f / fmaxf((float)(end - start), 1.f);
    Ax[(size_t)n * F_IN + lane] = f2bf(ax * inv);
    As_u[(size_t)n * 64 + lane] = packbf(s0 * inv, s1 * inv);
}

/* ------- agg2: wave/node; gather rs_bf; normalize; write A_rs (bf16) ------- */
__global__ __launch_bounds__(256) void k_agg2(
        const unsigned short* __restrict__ csr, const int* __restrict__ rs,
        const unsigned* __restrict__ rs_bfu, unsigned* __restrict__ Ars_u) {
    const int n = blockIdx.x * 4 + (threadIdx.x >> 6);
    const int lane  = threadIdx.x & 63;
    const int end   = rs[n];
    const int start = n ? rs[n - 1] : 0;
    float a0 = 0.f, a1 = 0.f;
    for (int e = start; e < end; ++e) {
        const int se = csr[e];
        const unsigned v = rs_bfu[(size_t)se * 64 + lane];
        a0 += bf2f((unsigned short)(v & 0xffffu));
        a1 += bf2f((unsigned short)(v >> 16));
    }
    const float inv = 1.f / fmaxf((float)(end - start), 1.f);
    Ars_u[(size_t)n * 64 + lane] = packbf(a0 * inv, a1 * inv);
}

/* ------- GEMM 1 (MFMA): [Ax|As] @ Wru_bf -> sigmoid -> rs_bf (in place over As), u --
 * 64 rows x 256 cols per block, 4 waves (16-row stripe each). W frags from global
 * (L2-resident bf16, pre-transposed). LDS: At[64][200] only -> high occupancy.    */
__global__ __launch_bounds__(256) void k_gemm_ru(
        const unsigned short* __restrict__ Ax, const unsigned short* __restrict__ As,
        const unsigned short* __restrict__ Wbf, const float* __restrict__ b,
        const float* __restrict__ states,
        unsigned short* __restrict__ rs_bf, float* __restrict__ u_out) {
    __shared__ unsigned short At[64][200];
    const int t  = threadIdx.x;
    const int n0 = blockIdx.x * 64;

    /* stage: cols 0..63 from Ax, 64..191 from As */
    #pragma unroll
    for (int it = 0; it < 2; ++it) {
        const int task = t + 256 * it, row = task >> 3, g = task & 7;
        const int n = n0 + row;
        uint4 v = make_uint4(0u, 0u, 0u, 0u);
        if (n < N_NODES) v = *(const uint4*)(Ax + (size_t)n * F_IN + g * 8);
        *(uint4*)(&At[row][g * 8]) = v;
    }
    #pragma unroll
    for (int it = 0; it < 4; ++it) {
        const int task = t + 256 * it, row = task >> 4, g = task & 15;
        const int n = n0 + row;
        uint4 v = make_uint4(0u, 0u, 0u, 0u);
        if (n < N_NODES) v = *(const uint4*)(As + (size_t)n * HID + g * 8);
        *(uint4*)(&At[row][F_IN + g * 8]) = v;
    }
    __syncthreads();

    const int lane = t & 63, wave = t >> 6;
    const int fr = lane & 15;
    const int fk = (lane >> 4) * 8;
    const unsigned short* pa = &At[wave * 16 + fr][fk];

    f32x4 acc[16] = {};
    #pragma unroll
    for (int k0 = 0; k0 < 6; ++k0) {
        const short8 a = *(const short8*)(pa + k0 * 32);
        #pragma unroll
        for (int ct = 0; ct < 16; ++ct) {
            const short8 bw = *(const short8*)(Wbf + (size_t)(ct * 16 + fr) * FIN + k0 * 32 + fk);
            acc[ct] = __builtin_amdgcn_mfma_f32_16x16x32_bf16(a, bw, acc[ct], 0, 0, 0);
        }
    }

    const int rbase = n0 + wave * 16 + (lane >> 4) * 4;
    #pragma unroll
    for (int ct = 0; ct < 16; ++ct) {
        const int col = ct * 16 + fr;
        const float bias = b[col];
        #pragma unroll
        for (int i = 0; i < 4; ++i) {
            const int n = rbase + i;
            if (n < N_NODES) {
                const float v = sigf(acc[ct][i] + bias);
                if (col < HID) {   /* r-gate: fuse r*states, store bf16 in place */
                    const float st = states[(size_t)n * HID + col];
                    rs_bf[(size_t)n * HID + col] = f2bf(v * st);
                } else {
                    u_out[(size_t)n * HID + (col - HID)] = v;
                }
            }
        }
    }
}

/* ------- GEMM 2 (MFMA): [Ax|A_rs] @ Wc_bf -> tanh -> gate -> new_state --------- */
__global__ __launch_bounds__(256) void k_gemm_c(
        const unsigned short* __restrict__ Ax, const unsigned short* __restrict__ Ars,
        const unsigned short* __restrict__ Wbf, const float* __restrict__ b,
        const float* __restrict__ states, const float* __restrict__ u_in,
        float* __restrict__ out1, float* __restrict__ out2) {
    __shared__ unsigned short At[64][200];
    const int t  = threadIdx.x;
    const int n0 = blockIdx.x * 64;

    #pragma unroll
    for (int it = 0; it < 2; ++it) {
        const int task = t + 256 * it, row = task >> 3, g = task & 7;
        const int n = n0 + row;
        uint4 v = make_uint4(0u, 0u, 0u, 0u);
        if (n < N_NODES) v = *(const uint4*)(Ax + (size_t)n * F_IN + g * 8);
        *(uint4*)(&At[row][g * 8]) = v;
    }
    #pragma unroll
    for (int it = 0; it < 4; ++it) {
        const int task = t + 256 * it, row = task >> 4, g = task & 15;
        const int n = n0 + row;
        uint4 v = make_uint4(0u, 0u, 0u, 0u);
        if (n < N_NODES) v = *(const uint4*)(Ars + (size_t)n * HID + g * 8);
        *(uint4*)(&At[row][F_IN + g * 8]) = v;
    }
    __syncthreads();

    const int lane = t & 63, wave = t >> 6;
    const int fr = lane & 15;
    const int fk = (lane >> 4) * 8;
    const unsigned short* pa = &At[wave * 16 + fr][fk];

    f32x4 acc[8] = {};
    #pragma unroll
    for (int k0 = 0; k0 < 6; ++k0) {
        const short8 a = *(const short8*)(pa + k0 * 32);
        #pragma unroll
        for (int ct = 0; ct < 8; ++ct) {
            const short8 bw = *(const short8*)(Wbf + (size_t)(ct * 16 + fr) * FIN + k0 * 32 + fk);
            acc[ct] = __builtin_amdgcn_mfma_f32_16x16x32_bf16(a, bw, acc[ct], 0, 0, 0);
        }
    }

    const int rbase = n0 + wave * 16 + (lane >> 4) * 4;
    #pragma unroll
    for (int ct = 0; ct < 8; ++ct) {
        const int col = ct * 16 + fr;
        const float bias = b[col];
        #pragma unroll
        for (int i = 0; i < 4; ++i) {
            const int n = rbase + i;
            if (n < N_NODES) {
                const size_t idx = (size_t)n * HID + col;
                const float c  = tanhf(acc[ct][i] + bias);
                const float uu = u_in[idx];
                const float st = states[idx];
                const float ns = uu * st + (1.f - uu) * c;
                out1[idx] = ns;
                out2[idx] = ns;
            }
        }
    }
}

extern "C" void kernel_launch(void* const* d_in, const int* in_sizes, int n_in,
                              void* d_out, int out_size, void* d_ws, size_t ws_size,
                              hipStream_t stream) {
    const float* inputs = (const float*)d_in[0];
    const float* states = (const float*)d_in[1];
    const int*   ei     = (const int*)d_in[2];
    const float* W_ru   = (const float*)d_in[3];
    const float* b_ru   = (const float*)d_in[4];
    const float* W_c    = (const float*)d_in[5];
    const float* b_c    = (const float*)d_in[6];

    float* out  = (float*)d_out;
    float* out1 = out;                             /* x_bf early, new_state at end */
    float* out2 = out + (size_t)N_NODES * HID;     /* u, then new_state */

    char* ws = (char*)d_ws;
    int*            rs     = (int*)(ws + RS_OFF);
    unsigned short* csr    = (unsigned short*)(ws + CSR_OFF);
    int*            bsum   = (int*)(ws + BSUM_OFF);
    unsigned short* Wru_bf = (unsigned short*)(ws + WRU_OFF);
    unsigned short* Wc_bf  = (unsigned short*)(ws + WC_OFF);
    unsigned short* s_bf   = (unsigned short*)(ws + SBF_OFF);  /* counts + A_rs alias */
    unsigned short* Ax     = (unsigned short*)(ws + AX_OFF);
    unsigned short* As     = (unsigned short*)(ws + AS_OFF);   /* rs_bf alias (in place) */
    int*            counts = (int*)(ws + SBF_OFF);
    unsigned short* Ars    = s_bf;
    unsigned short* x_bf   = (unsigned short*)d_out;           /* first 6.4MB of out1 */

    const int* src = ei;
    const int* dst = ei + N_EDGES;

    const int egrid     = (N_EDGES + 255) / 256;   /* 1563  */
    const int agg_grid  = N_NODES / 4;             /* 12500 */
    const int gemm_grid = (N_NODES + 63) / 64;     /* 782   */
    const int prep_grid = (N_NODES * HID / 4 + N_NODES * F_IN / 4) / 256;  /* 9375 */
    const int prepw_grid = (FIN * RU + FIN * HID) / 256;                   /* 288  */

    hipMemsetAsync(counts, 0, N_NODES * sizeof(int), stream);
    k_hist  <<<egrid, 256, 0, stream>>>(dst, counts);
    k_scan_a<<<NSCAN, 256, 0, stream>>>(counts, bsum);
    k_scan_b<<<1,     256, 0, stream>>>(bsum);
    k_scan_c<<<NSCAN, 256, 0, stream>>>(counts, bsum, rs);
    k_fill  <<<egrid, 256, 0, stream>>>(src, dst, rs, csr);
    k_prepW <<<prepw_grid, 256, 0, stream>>>(W_ru, W_c, Wru_bf, Wc_bf);
    k_prep  <<<prep_grid, 256, 0, stream>>>(states, inputs, (uint2*)s_bf, (uint2*)x_bf);
    k_agg1  <<<agg_grid, 256, 0, stream>>>(csr, rs, x_bf, (const unsigned*)s_bf,
                                           Ax, (unsigned*)As);
    k_gemm_ru<<<gemm_grid, 256, 0, stream>>>(Ax, As, Wru_bf, b_ru, states,
                                             As /* in-place rs_bf */, out2);
    k_agg2  <<<agg_grid, 256, 0, stream>>>(csr, rs, (const unsigned*)As, (unsigned*)Ars);
    k_gemm_c<<<gemm_grid, 256, 0, stream>>>(Ax, Ars, Wc_bf, b_c, states,
                                            out2, out1, out2);
}

// Round 6
// 254.871 us; speedup vs baseline: 1.1538x; 1.1538x over previous
//
#include <hip/hip_runtime.h>
#include <hip/hip_bf16.h>
#include <math.h>

#define N_NODES 50000
#define N_EDGES 400000
#define F_IN    64
#define HID     128
#define FIN     192   /* F_IN + HID */
#define RU      256   /* 2*HID */

#define NSCAN   196   /* ceil(N_NODES/256) */

/* ---- ws layout (byte offsets), total ~33.2 MB ----
   rs     : int[N_NODES]          @ RS_OFF   CSR starts (mutated to ends by fill)
   csr    : ushort[N_EDGES]       @ CSR_OFF
   bsum   : int[256]              @ BSUM_OFF
   Wru_bf : bf16[RU][FIN]         @ WRU_OFF  (transposed W_ru)
   Wc_bf  : bf16[HID][FIN]        @ WC_OFF   (transposed W_c)
   s_bf   : bf16[N][HID]          @ SBF_OFF  written by prep, read by agg1;
                                             THEN rs_bf (written by gemm_ru, read by agg2).
                                             counts[] aliased pre-prep.
   Ax     : bf16[N][F_IN]         @ AX_OFF   agg1 -> gemm_ru, gemm_c
   As     : bf16[N][HID]          @ AS_OFF   agg1 -> gemm_ru;
                                             THEN Ars (written by agg2, read by gemm_c)
   x_bf   : bf16[N][F_IN]  lives in d_out[0:6.4MB] (dead before gemm_c writes out1) */
#define RS_OFF    0u
#define CSR_OFF   200064u
#define BSUM_OFF  1000064u
#define WRU_OFF   1001088u
#define WC_OFF    1099392u
#define SBF_OFF   1148544u
#define AX_OFF    13948544u
#define AS_OFF    20348544u

typedef __attribute__((ext_vector_type(8))) short short8;
typedef __attribute__((ext_vector_type(4))) float f32x4;

__device__ __forceinline__ float sigf(float x) { return 1.f / (1.f + expf(-x)); }
__device__ __forceinline__ float bf2f(unsigned short h) {
    return __uint_as_float(((unsigned)h) << 16);
}
__device__ __forceinline__ unsigned short f2bf(float f) { /* RNE */
    unsigned u = __float_as_uint(f);
    return (unsigned short)((u + 0x7fff + ((u >> 16) & 1)) >> 16);
}
__device__ __forceinline__ unsigned packbf(float lo, float hi) {
    return ((unsigned)f2bf(hi) << 16) | (unsigned)f2bf(lo);
}

/* ---------------- CSR build ---------------- */
__global__ void k_hist(const int* __restrict__ dst, int* __restrict__ counts) {
    const int e = blockIdx.x * 256 + threadIdx.x;
    if (e < N_EDGES) atomicAdd(&counts[dst[e]], 1);
}

__device__ __forceinline__ int excl_scan_256(int v, int* tmp) {
    const int t = threadIdx.x;
    tmp[t] = v; __syncthreads();
    #pragma unroll
    for (int off = 1; off < 256; off <<= 1) {
        int u = (t >= off) ? tmp[t - off] : 0;
        __syncthreads();
        tmp[t] += u;
        __syncthreads();
    }
    return tmp[t] - v;
}

__global__ void k_scan_a(const int* __restrict__ counts, int* __restrict__ bsum) {
    __shared__ int tmp[256];
    const int i = blockIdx.x * 256 + threadIdx.x;
    const int v = (i < N_NODES) ? counts[i] : 0;
    excl_scan_256(v, tmp);
    if (threadIdx.x == 255) bsum[blockIdx.x] = tmp[255];
}

__global__ void k_scan_b(int* __restrict__ bsum) {
    __shared__ int tmp[256];
    const int t = threadIdx.x;
    const int v = (t < NSCAN) ? bsum[t] : 0;
    const int e = excl_scan_256(v, tmp);
    bsum[t] = e;
}

__global__ void k_scan_c(const int* __restrict__ counts, const int* __restrict__ bsum,
                         int* __restrict__ rs) {
    __shared__ int tmp[256];
    const int i = blockIdx.x * 256 + threadIdx.x;
    const int v = (i < N_NODES) ? counts[i] : 0;
    const int e = excl_scan_256(v, tmp);
    if (i < N_NODES) rs[i] = bsum[blockIdx.x] + e;
}

__global__ void k_fill(const int* __restrict__ src, const int* __restrict__ dst,
                       int* __restrict__ rs, unsigned short* __restrict__ csr) {
    const int e = blockIdx.x * 256 + threadIdx.x;
    if (e < N_EDGES) {
        const int pos = atomicAdd(&rs[dst[e]], 1);
        csr[pos] = (unsigned short)src[e];
    }
}

/* ------- prepW: transpose W to [col][k] and convert f32->bf16 ------- */
__global__ void k_prepW(const float* __restrict__ Wru, const float* __restrict__ Wc,
                        unsigned short* __restrict__ Wru_bf,
                        unsigned short* __restrict__ Wc_bf) {
    const int t = blockIdx.x * 256 + threadIdx.x;   /* 73728 threads exact */
    if (t < FIN * RU) {
        const int k = t >> 8, c = t & 255;
        Wru_bf[c * FIN + k] = f2bf(Wru[t]);
    } else {
        const int tt = t - FIN * RU;
        const int k = tt >> 7, c = tt & 127;
        Wc_bf[c * FIN + k] = f2bf(Wc[tt]);
    }
}

/* ------- prep: states -> s_bf, inputs -> x_bf (bf16 gather tables) ------- */
__global__ void k_prep(const float* __restrict__ states, const float* __restrict__ inputs,
                       uint2* __restrict__ s_bf2, uint2* __restrict__ x_bf2) {
    const int t = blockIdx.x * 256 + threadIdx.x;   /* 2.4M threads exact */
    if (t < N_NODES * HID / 4) {
        const float4 v = ((const float4*)states)[t];
        s_bf2[t] = make_uint2(packbf(v.x, v.y), packbf(v.z, v.w));
    } else {
        const int j = t - N_NODES * HID / 4;
        const float4 v = ((const float4*)inputs)[j];
        x_bf2[j] = make_uint2(packbf(v.x, v.y), packbf(v.z, v.w));
    }
}

/* ------- agg1: wave/node; gather x_bf,s_bf; normalize; write Ax,As (bf16) ------- */
__global__ __launch_bounds__(256) void k_agg1(
        const unsigned short* __restrict__ csr, const int* __restrict__ rs,
        const unsigned short* __restrict__ x_bf, const unsigned* __restrict__ s_bfu,
        unsigned short* __restrict__ Ax, unsigned* __restrict__ As_u) {
    const int n = blockIdx.x * 4 + (threadIdx.x >> 6);
    const int lane  = threadIdx.x & 63;
    const int end   = rs[n];
    const int start = n ? rs[n - 1] : 0;
    float ax = 0.f, s0 = 0.f, s1 = 0.f;
    for (int e = start; e < end; ++e) {
        const int se = csr[e];
        ax += bf2f(x_bf[(size_t)se * F_IN + lane]);
        const unsigned sv = s_bfu[(size_t)se * 64 + lane];
        s0 += bf2f((unsigned short)(sv & 0xffffu));
        s1 += bf2f((unsigned short)(sv >> 16));
    }
    const float inv = 1.f / fmaxf((float)(end - start), 1.f);
    Ax[(size_t)n * F_IN + lane] = f2bf(ax * inv);
    As_u[(size_t)n * 64 + lane] = packbf(s0 * inv, s1 * inv);
}

/* ------- agg2: wave/node; gather rs_bf; normalize; write Ars (bf16) ------- */
__global__ __launch_bounds__(256) void k_agg2(
        const unsigned short* __restrict__ csr, const int* __restrict__ rs,
        const unsigned* __restrict__ rs_bfu, unsigned* __restrict__ Ars_u) {
    const int n = blockIdx.x * 4 + (threadIdx.x >> 6);
    const int lane  = threadIdx.x & 63;
    const int end   = rs[n];
    const int start = n ? rs[n - 1] : 0;
    float a0 = 0.f, a1 = 0.f;
    for (int e = start; e < end; ++e) {
        const int se = csr[e];
        const unsigned v = rs_bfu[(size_t)se * 64 + lane];
        a0 += bf2f((unsigned short)(v & 0xffffu));
        a1 += bf2f((unsigned short)(v >> 16));
    }
    const float inv = 1.f / fmaxf((float)(end - start), 1.f);
    Ars_u[(size_t)n * 64 + lane] = packbf(a0 * inv, a1 * inv);
}

/* ------- GEMM 1 (MFMA): [Ax|As] @ Wru_bf -> sigmoid -> rs_bf / u -------
 * grid (782, 2): 64 rows x 128 cols per block; 4 waves, one 16-row stripe each.
 * LDS: At[64][200] + Wt[128][200] bf16 (76.8 KB -> 2 blocks/CU). W staging is a
 * pure coalesced memcpy from pre-transposed bf16 Wbf (round-5 regression was
 * per-MFMA global W reads: latency-bound at 19% occupancy, MfmaUtil 1.9%).  */
__global__ __launch_bounds__(256) void k_gemm_ru(
        const unsigned short* __restrict__ Ax, const unsigned short* __restrict__ As,
        const unsigned short* __restrict__ Wbf, const float* __restrict__ b,
        const float* __restrict__ states,
        unsigned short* __restrict__ rs_bf, float* __restrict__ u_out) {
    __shared__ unsigned short At[64][200];
    __shared__ unsigned short Wt[128][200];
    const int t  = threadIdx.x;
    const int n0 = blockIdx.x * 64;
    const int cb = blockIdx.y;            /* 0 -> r half (cols 0..127), 1 -> u half */

    /* stage A: cols 0..63 from Ax, 64..191 from As */
    #pragma unroll
    for (int it = 0; it < 2; ++it) {
        const int task = t + 256 * it, row = task >> 3, g = task & 7;
        const int n = n0 + row;
        uint4 v = make_uint4(0u, 0u, 0u, 0u);
        if (n < N_NODES) v = *(const uint4*)(Ax + (size_t)n * F_IN + g * 8);
        *(uint4*)(&At[row][g * 8]) = v;
    }
    #pragma unroll
    for (int it = 0; it < 4; ++it) {
        const int task = t + 256 * it, row = task >> 4, g = task & 15;
        const int n = n0 + row;
        uint4 v = make_uint4(0u, 0u, 0u, 0u);
        if (n < N_NODES) v = *(const uint4*)(As + (size_t)n * HID + g * 8);
        *(uint4*)(&At[row][F_IN + g * 8]) = v;
    }
    /* stage Wt: 128 rows x 192 elems = 3072 uint4, coalesced memcpy */
    #pragma unroll
    for (int it = 0; it < 12; ++it) {
        const int task = t + 256 * it;
        const int c = task / 24, g = task - c * 24;
        *(uint4*)(&Wt[c][g * 8]) =
            *(const uint4*)(Wbf + (size_t)(cb * 128 + c) * FIN + g * 8);
    }
    __syncthreads();

    const int lane = t & 63, wave = t >> 6;
    const int fr = lane & 15;
    const int fk = (lane >> 4) * 8;
    const unsigned short* pa = &At[wave * 16 + fr][fk];

    f32x4 acc[8] = {};
    #pragma unroll
    for (int k0 = 0; k0 < 6; ++k0) {
        const short8 a = *(const short8*)(pa + k0 * 32);
        #pragma unroll
        for (int ct = 0; ct < 8; ++ct) {
            const short8 bw = *(const short8*)(&Wt[ct * 16 + fr][fk + k0 * 32]);
            acc[ct] = __builtin_amdgcn_mfma_f32_16x16x32_bf16(a, bw, acc[ct], 0, 0, 0);
        }
    }

    const int rbase = n0 + wave * 16 + (lane >> 4) * 4;
    #pragma unroll
    for (int ct = 0; ct < 8; ++ct) {
        const int colrel = ct * 16 + fr;
        const float bias = b[cb * 128 + colrel];
        #pragma unroll
        for (int i = 0; i < 4; ++i) {
            const int n = rbase + i;
            if (n < N_NODES) {
                const float v = sigf(acc[ct][i] + bias);
                const size_t idx = (size_t)n * HID + colrel;
                if (cb == 0) {   /* r-gate: fuse r*states, store bf16 to s_bf region */
                    rs_bf[idx] = f2bf(v * states[idx]);
                } else {
                    u_out[idx] = v;
                }
            }
        }
    }
}

/* ------- GEMM 2 (MFMA): [Ax|Ars] @ Wc_bf -> tanh -> gate -> new_state ------- */
__global__ __launch_bounds__(256) void k_gemm_c(
        const unsigned short* __restrict__ Ax, const unsigned short* __restrict__ Ars,
        const unsigned short* __restrict__ Wbf, const float* __restrict__ b,
        const float* __restrict__ states, const float* __restrict__ u_in,
        float* __restrict__ out1, float* __restrict__ out2) {
    __shared__ unsigned short At[64][200];
    __shared__ unsigned short Wt[128][200];
    const int t  = threadIdx.x;
    const int n0 = blockIdx.x * 64;

    #pragma unroll
    for (int it = 0; it < 2; ++it) {
        const int task = t + 256 * it, row = task >> 3, g = task & 7;
        const int n = n0 + row;
        uint4 v = make_uint4(0u, 0u, 0u, 0u);
        if (n < N_NODES) v = *(const uint4*)(Ax + (size_t)n * F_IN + g * 8);
        *(uint4*)(&At[row][g * 8]) = v;
    }
    #pragma unroll
    for (int it = 0; it < 4; ++it) {
        const int task = t + 256 * it, row = task >> 4, g = task & 15;
        const int n = n0 + row;
        uint4 v = make_uint4(0u, 0u, 0u, 0u);
        if (n < N_NODES) v = *(const uint4*)(Ars + (size_t)n * HID + g * 8);
        *(uint4*)(&At[row][F_IN + g * 8]) = v;
    }
    #pragma unroll
    for (int it = 0; it < 12; ++it) {
        const int task = t + 256 * it;
        const int c = task / 24, g = task - c * 24;
        *(uint4*)(&Wt[c][g * 8]) = *(const uint4*)(Wbf + (size_t)c * FIN + g * 8);
    }
    __syncthreads();

    const int lane = t & 63, wave = t >> 6;
    const int fr = lane & 15;
    const int fk = (lane >> 4) * 8;
    const unsigned short* pa = &At[wave * 16 + fr][fk];

    f32x4 acc[8] = {};
    #pragma unroll
    for (int k0 = 0; k0 < 6; ++k0) {
        const short8 a = *(const short8*)(pa + k0 * 32);
        #pragma unroll
        for (int ct = 0; ct < 8; ++ct) {
            const short8 bw = *(const short8*)(&Wt[ct * 16 + fr][fk + k0 * 32]);
            acc[ct] = __builtin_amdgcn_mfma_f32_16x16x32_bf16(a, bw, acc[ct], 0, 0, 0);
        }
    }

    const int rbase = n0 + wave * 16 + (lane >> 4) * 4;
    #pragma unroll
    for (int ct = 0; ct < 8; ++ct) {
        const int col = ct * 16 + fr;
        const float bias = b[col];
        #pragma unroll
        for (int i = 0; i < 4; ++i) {
            const int n = rbase + i;
            if (n < N_NODES) {
                const size_t idx = (size_t)n * HID + col;
                const float c  = tanhf(acc[ct][i] + bias);
                const float uu = u_in[idx];
                const float st = states[idx];
                const float ns = uu * st + (1.f - uu) * c;
                out1[idx] = ns;
                out2[idx] = ns;
            }
        }
    }
}

extern "C" void kernel_launch(void* const* d_in, const int* in_sizes, int n_in,
                              void* d_out, int out_size, void* d_ws, size_t ws_size,
                              hipStream_t stream) {
    const float* inputs = (const float*)d_in[0];
    const float* states = (const float*)d_in[1];
    const int*   ei     = (const int*)d_in[2];
    const float* W_ru   = (const float*)d_in[3];
    const float* b_ru   = (const float*)d_in[4];
    const float* W_c    = (const float*)d_in[5];
    const float* b_c    = (const float*)d_in[6];

    float* out  = (float*)d_out;
    float* out1 = out;                             /* x_bf early, new_state at end */
    float* out2 = out + (size_t)N_NODES * HID;     /* u, then new_state */

    char* ws = (char*)d_ws;
    int*            rs     = (int*)(ws + RS_OFF);
    unsigned short* csr    = (unsigned short*)(ws + CSR_OFF);
    int*            bsum   = (int*)(ws + BSUM_OFF);
    unsigned short* Wru_bf = (unsigned short*)(ws + WRU_OFF);
    unsigned short* Wc_bf  = (unsigned short*)(ws + WC_OFF);
    unsigned short* s_bf   = (unsigned short*)(ws + SBF_OFF);  /* then rs_bf */
    unsigned short* Ax     = (unsigned short*)(ws + AX_OFF);
    unsigned short* As     = (unsigned short*)(ws + AS_OFF);   /* then Ars */
    int*            counts = (int*)(ws + SBF_OFF);             /* dead before prep */
    unsigned short* x_bf   = (unsigned short*)d_out;           /* first 6.4MB of out1 */

    const int* src = ei;
    const int* dst = ei + N_EDGES;

    const int egrid      = (N_EDGES + 255) / 256;  /* 1563  */
    const int agg_grid   = N_NODES / 4;            /* 12500 */
    const int gemm_grid  = (N_NODES + 63) / 64;    /* 782   */
    const int prep_grid  = (N_NODES * HID / 4 + N_NODES * F_IN / 4) / 256;  /* 9375 */
    const int prepw_grid = (FIN * RU + FIN * HID) / 256;                    /* 288  */

    hipMemsetAsync(counts, 0, N_NODES * sizeof(int), stream);
    k_hist  <<<egrid, 256, 0, stream>>>(dst, counts);
    k_scan_a<<<NSCAN, 256, 0, stream>>>(counts, bsum);
    k_scan_b<<<1,     256, 0, stream>>>(bsum);
    k_scan_c<<<NSCAN, 256, 0, stream>>>(counts, bsum, rs);
    k_fill  <<<egrid, 256, 0, stream>>>(src, dst, rs, csr);
    k_prepW <<<prepw_grid, 256, 0, stream>>>(W_ru, W_c, Wru_bf, Wc_bf);
    k_prep  <<<prep_grid, 256, 0, stream>>>(states, inputs, (uint2*)s_bf, (uint2*)x_bf);
    k_agg1  <<<agg_grid, 256, 0, stream>>>(csr, rs, x_bf, (const unsigned*)s_bf,
                                           Ax, (unsigned*)As);
    k_gemm_ru<<<dim3(gemm_grid, 2), 256, 0, stream>>>(Ax, As, Wru_bf, b_ru, states,
                                                      s_bf /* rs_bf */, out2);
    k_agg2  <<<agg_grid, 256, 0, stream>>>(csr, rs, (const unsigned*)s_bf,
                                           (unsigned*)As /* Ars */);
    k_gemm_c<<<gemm_grid, 256, 0, stream>>>(Ax, As /* Ars */, Wc_bf, b_c, states,
                                            out2, out1, out2);
}

// Round 7
// 232.159 us; speedup vs baseline: 1.2666x; 1.0978x over previous
//
#include <hip/hip_runtime.h>
#include <hip/hip_bf16.h>
#include <math.h>

#define N_NODES 50000
#define N_EDGES 400000
#define F_IN    64
#define HID     128
#define FIN     192   /* F_IN + HID */
#define RU      256   /* 2*HID */

#define NSCAN   196   /* ceil(N_NODES/256) */

/* ---- ws layout (byte offsets), total ~33.2 MB ----
   rs     : int[N_NODES]          @ RS_OFF   CSR starts (mutated to ends by fill)
   csr    : ushort[N_EDGES]       @ CSR_OFF
   bsum   : int[256]              @ BSUM_OFF
   Wru_bf : bf16[RU][FIN]         @ WRU_OFF  (transposed W_ru)
   Wc_bf  : bf16[HID][FIN]        @ WC_OFF   (transposed W_c)
   s_bf   : bf16[N][HID]          @ SBF_OFF  prep -> agg1; THEN rs_bf (gemm_ru -> agg2).
                                             counts[] aliased pre-prep.
   Ax     : bf16[N][F_IN]         @ AX_OFF   agg1 -> gemm_ru, gemm_c
   As     : bf16[N][HID]          @ AS_OFF   agg1 -> gemm_ru; THEN Ars (agg2 -> gemm_c)
   x_bf   : bf16[N][F_IN]  lives in d_out[0:6.4MB] (dead before gemm_c writes out1) */
#define RS_OFF    0u
#define CSR_OFF   200064u
#define BSUM_OFF  1000064u
#define WRU_OFF   1001088u
#define WC_OFF    1099392u
#define SBF_OFF   1148544u
#define AX_OFF    13948544u
#define AS_OFF    20348544u

typedef __attribute__((ext_vector_type(8))) short short8;
typedef __attribute__((ext_vector_type(4))) float f32x4;

__device__ __forceinline__ float sigf(float x) { return 1.f / (1.f + expf(-x)); }
__device__ __forceinline__ float bf2f(unsigned short h) {
    return __uint_as_float(((unsigned)h) << 16);
}
__device__ __forceinline__ unsigned short f2bf(float f) { /* RNE */
    unsigned u = __float_as_uint(f);
    return (unsigned short)((u + 0x7fff + ((u >> 16) & 1)) >> 16);
}
__device__ __forceinline__ unsigned packbf(float lo, float hi) {
    return ((unsigned)f2bf(hi) << 16) | (unsigned)f2bf(lo);
}

/* ---------------- CSR build ---------------- */
__global__ void k_hist(const int* __restrict__ dst, int* __restrict__ counts) {
    const int e = blockIdx.x * 256 + threadIdx.x;
    if (e < N_EDGES) atomicAdd(&counts[dst[e]], 1);
}

__device__ __forceinline__ int excl_scan_256(int v, int* tmp) {
    const int t = threadIdx.x;
    tmp[t] = v; __syncthreads();
    #pragma unroll
    for (int off = 1; off < 256; off <<= 1) {
        int u = (t >= off) ? tmp[t - off] : 0;
        __syncthreads();
        tmp[t] += u;
        __syncthreads();
    }
    return tmp[t] - v;
}

__global__ void k_scan_a(const int* __restrict__ counts, int* __restrict__ bsum) {
    __shared__ int tmp[256];
    const int i = blockIdx.x * 256 + threadIdx.x;
    const int v = (i < N_NODES) ? counts[i] : 0;
    excl_scan_256(v, tmp);
    if (threadIdx.x == 255) bsum[blockIdx.x] = tmp[255];
}

__global__ void k_scan_b(int* __restrict__ bsum) {
    __shared__ int tmp[256];
    const int t = threadIdx.x;
    const int v = (t < NSCAN) ? bsum[t] : 0;
    const int e = excl_scan_256(v, tmp);
    bsum[t] = e;
}

__global__ void k_scan_c(const int* __restrict__ counts, const int* __restrict__ bsum,
                         int* __restrict__ rs) {
    __shared__ int tmp[256];
    const int i = blockIdx.x * 256 + threadIdx.x;
    const int v = (i < N_NODES) ? counts[i] : 0;
    const int e = excl_scan_256(v, tmp);
    if (i < N_NODES) rs[i] = bsum[blockIdx.x] + e;
}

__global__ void k_fill(const int* __restrict__ src, const int* __restrict__ dst,
                       int* __restrict__ rs, unsigned short* __restrict__ csr) {
    const int e = blockIdx.x * 256 + threadIdx.x;
    if (e < N_EDGES) {
        const int pos = atomicAdd(&rs[dst[e]], 1);
        csr[pos] = (unsigned short)src[e];
    }
}

/* ------- prepW: transpose W to [col][k] and convert f32->bf16 ------- */
__global__ void k_prepW(const float* __restrict__ Wru, const float* __restrict__ Wc,
                        unsigned short* __restrict__ Wru_bf,
                        unsigned short* __restrict__ Wc_bf) {
    const int t = blockIdx.x * 256 + threadIdx.x;   /* 73728 threads exact */
    if (t < FIN * RU) {
        const int k = t >> 8, c = t & 255;
        Wru_bf[c * FIN + k] = f2bf(Wru[t]);
    } else {
        const int tt = t - FIN * RU;
        const int k = tt >> 7, c = tt & 127;
        Wc_bf[c * FIN + k] = f2bf(Wc[tt]);
    }
}

/* ------- prep: states -> s_bf, inputs -> x_bf (bf16 gather tables) ------- */
__global__ void k_prep(const float* __restrict__ states, const float* __restrict__ inputs,
                       uint2* __restrict__ s_bf2, uint2* __restrict__ x_bf2) {
    const int t = blockIdx.x * 256 + threadIdx.x;   /* 2.4M threads exact */
    if (t < N_NODES * HID / 4) {
        const float4 v = ((const float4*)states)[t];
        s_bf2[t] = make_uint2(packbf(v.x, v.y), packbf(v.z, v.w));
    } else {
        const int j = t - N_NODES * HID / 4;
        const float4 v = ((const float4*)inputs)[j];
        x_bf2[j] = make_uint2(packbf(v.x, v.y), packbf(v.z, v.w));
    }
}

/* ------- agg1: wave/node; gather x_bf,s_bf; normalize; write Ax,As (bf16) ------- */
__global__ __launch_bounds__(256) void k_agg1(
        const unsigned short* __restrict__ csr, const int* __restrict__ rs,
        const unsigned short* __restrict__ x_bf, const unsigned* __restrict__ s_bfu,
        unsigned short* __restrict__ Ax, unsigned* __restrict__ As_u) {
    const int n = blockIdx.x * 4 + (threadIdx.x >> 6);
    const int lane  = threadIdx.x & 63;
    const int end   = rs[n];
    const int start = n ? rs[n - 1] : 0;
    float ax = 0.f, s0 = 0.f, s1 = 0.f;
    for (int e = start; e < end; ++e) {
        const int se = csr[e];
        ax += bf2f(x_bf[(size_t)se * F_IN + lane]);
        const unsigned sv = s_bfu[(size_t)se * 64 + lane];
        s0 += bf2f((unsigned short)(sv & 0xffffu));
        s1 += bf2f((unsigned short)(sv >> 16));
    }
    const float inv = 1.f / fmaxf((float)(end - start), 1.f);
    Ax[(size_t)n * F_IN + lane] = f2bf(ax * inv);
    As_u[(size_t)n * 64 + lane] = packbf(s0 * inv, s1 * inv);
}

/* ------- agg2: wave/node; gather rs_bf; normalize; write Ars (bf16) ------- */
__global__ __launch_bounds__(256) void k_agg2(
        const unsigned short* __restrict__ csr, const int* __restrict__ rs,
        const unsigned* __restrict__ rs_bfu, unsigned* __restrict__ Ars_u) {
    const int n = blockIdx.x * 4 + (threadIdx.x >> 6);
    const int lane  = threadIdx.x & 63;
    const int end   = rs[n];
    const int start = n ? rs[n - 1] : 0;
    float a0 = 0.f, a1 = 0.f;
    for (int e = start; e < end; ++e) {
        const int se = csr[e];
        const unsigned v = rs_bfu[(size_t)se * 64 + lane];
        a0 += bf2f((unsigned short)(v & 0xffffu));
        a1 += bf2f((unsigned short)(v >> 16));
    }
    const float inv = 1.f / fmaxf((float)(end - start), 1.f);
    Ars_u[(size_t)n * 64 + lane] = packbf(a0 * inv, a1 * inv);
}

/* ------- GEMM 1 (MFMA): [Ax|As] @ Wru_bf -> sigmoid -> rs_bf / u -------
 * grid (391, 2): 128 rows x 128 cols per block; 4 waves, each owns TWO 16-row
 * stripes. A fragments load straight global->VGPR (line-coalesced: lanes kh=0..3
 * cover 64B per row) -- no A LDS, no bank conflicts, one barrier. Only Wt is
 * staged in LDS (51.2 KB -> 3 blocks/CU); each W ds_read feeds 2 MFMA.      */
__global__ __launch_bounds__(256, 3) void k_gemm_ru(
        const unsigned short* __restrict__ Ax, const unsigned short* __restrict__ As,
        const unsigned short* __restrict__ Wbf, const float* __restrict__ b,
        const float* __restrict__ states,
        unsigned short* __restrict__ rs_bf, float* __restrict__ u_out) {
    __shared__ unsigned short Wt[128][200];
    const int t  = threadIdx.x;
    const int n0 = blockIdx.x * 128;
    const int cb = blockIdx.y;            /* 0 -> r half (cols 0..127), 1 -> u half */

    /* stage Wt: 128 rows x 192 elems = 3072 uint4, coalesced memcpy */
    #pragma unroll
    for (int it = 0; it < 12; ++it) {
        const int task = t + 256 * it;
        const int c = task / 24, g = task - c * 24;
        *(uint4*)(&Wt[c][g * 8]) =
            *(const uint4*)(Wbf + (size_t)(cb * 128 + c) * FIN + g * 8);
    }

    const int lane = t & 63, wave = t >> 6;
    const int fr = lane & 15;             /* frag row (A) / col (B) */
    const int fk = (lane >> 4) * 8;       /* frag k sub-offset      */

    /* A fragments: 2 stripes x 6 k-steps, global->reg (no LDS) */
    short8 afr[2][6];
    const short8 zero = {};
    #pragma unroll
    for (int s = 0; s < 2; ++s) {
        const int n = n0 + wave * 32 + s * 16 + fr;
        if (n < N_NODES) {
            const unsigned short* axp = Ax + (size_t)n * F_IN + fk;
            const unsigned short* asp = As + (size_t)n * HID + fk;
            afr[s][0] = *(const short8*)(axp);
            afr[s][1] = *(const short8*)(axp + 32);
            afr[s][2] = *(const short8*)(asp);
            afr[s][3] = *(const short8*)(asp + 32);
            afr[s][4] = *(const short8*)(asp + 64);
            afr[s][5] = *(const short8*)(asp + 96);
        } else {
            #pragma unroll
            for (int j = 0; j < 6; ++j) afr[s][j] = zero;
        }
    }
    __syncthreads();

    f32x4 acc[2][8] = {};
    #pragma unroll
    for (int k0 = 0; k0 < 6; ++k0) {
        #pragma unroll
        for (int ct = 0; ct < 8; ++ct) {
            const short8 bw = *(const short8*)(&Wt[ct * 16 + fr][fk + k0 * 32]);
            acc[0][ct] = __builtin_amdgcn_mfma_f32_16x16x32_bf16(afr[0][k0], bw, acc[0][ct], 0, 0, 0);
            acc[1][ct] = __builtin_amdgcn_mfma_f32_16x16x32_bf16(afr[1][k0], bw, acc[1][ct], 0, 0, 0);
        }
    }

    #pragma unroll
    for (int s = 0; s < 2; ++s) {
        const int rbase = n0 + wave * 32 + s * 16 + (lane >> 4) * 4;
        #pragma unroll
        for (int ct = 0; ct < 8; ++ct) {
            const int colrel = ct * 16 + fr;
            const float bias = b[cb * 128 + colrel];
            #pragma unroll
            for (int i = 0; i < 4; ++i) {
                const int n = rbase + i;
                if (n < N_NODES) {
                    const float v = sigf(acc[s][ct][i] + bias);
                    const size_t idx = (size_t)n * HID + colrel;
                    if (cb == 0) {   /* r-gate: fuse r*states, store bf16 */
                        rs_bf[idx] = f2bf(v * states[idx]);
                    } else {
                        u_out[idx] = v;
                    }
                }
            }
        }
    }
}

/* ------- GEMM 2 (MFMA): [Ax|Ars] @ Wc_bf -> tanh -> gate -> new_state -------
 * grid (391): same structure as gemm_ru, single 128-col block.              */
__global__ __launch_bounds__(256, 3) void k_gemm_c(
        const unsigned short* __restrict__ Ax, const unsigned short* __restrict__ Ars,
        const unsigned short* __restrict__ Wbf, const float* __restrict__ b,
        const float* __restrict__ states, const float* __restrict__ u_in,
        float* __restrict__ out1, float* __restrict__ out2) {
    __shared__ unsigned short Wt[128][200];
    const int t  = threadIdx.x;
    const int n0 = blockIdx.x * 128;

    #pragma unroll
    for (int it = 0; it < 12; ++it) {
        const int task = t + 256 * it;
        const int c = task / 24, g = task - c * 24;
        *(uint4*)(&Wt[c][g * 8]) = *(const uint4*)(Wbf + (size_t)c * FIN + g * 8);
    }

    const int lane = t & 63, wave = t >> 6;
    const int fr = lane & 15;
    const int fk = (lane >> 4) * 8;

    short8 afr[2][6];
    const short8 zero = {};
    #pragma unroll
    for (int s = 0; s < 2; ++s) {
        const int n = n0 + wave * 32 + s * 16 + fr;
        if (n < N_NODES) {
            const unsigned short* axp = Ax  + (size_t)n * F_IN + fk;
            const unsigned short* arp = Ars + (size_t)n * HID + fk;
            afr[s][0] = *(const short8*)(axp);
            afr[s][1] = *(const short8*)(axp + 32);
            afr[s][2] = *(const short8*)(arp);
            afr[s][3] = *(const short8*)(arp + 32);
            afr[s][4] = *(const short8*)(arp + 64);
            afr[s][5] = *(const short8*)(arp + 96);
        } else {
            #pragma unroll
            for (int j = 0; j < 6; ++j) afr[s][j] = zero;
        }
    }
    __syncthreads();

    f32x4 acc[2][8] = {};
    #pragma unroll
    for (int k0 = 0; k0 < 6; ++k0) {
        #pragma unroll
        for (int ct = 0; ct < 8; ++ct) {
            const short8 bw = *(const short8*)(&Wt[ct * 16 + fr][fk + k0 * 32]);
            acc[0][ct] = __builtin_amdgcn_mfma_f32_16x16x32_bf16(afr[0][k0], bw, acc[0][ct], 0, 0, 0);
            acc[1][ct] = __builtin_amdgcn_mfma_f32_16x16x32_bf16(afr[1][k0], bw, acc[1][ct], 0, 0, 0);
        }
    }

    #pragma unroll
    for (int s = 0; s < 2; ++s) {
        const int rbase = n0 + wave * 32 + s * 16 + (lane >> 4) * 4;
        #pragma unroll
        for (int ct = 0; ct < 8; ++ct) {
            const int col = ct * 16 + fr;
            const float bias = b[col];
            #pragma unroll
            for (int i = 0; i < 4; ++i) {
                const int n = rbase + i;
                if (n < N_NODES) {
                    const size_t idx = (size_t)n * HID + col;
                    const float c  = tanhf(acc[s][ct][i] + bias);
                    const float uu = u_in[idx];
                    const float st = states[idx];
                    const float ns = uu * st + (1.f - uu) * c;
                    out1[idx] = ns;
                    out2[idx] = ns;
                }
            }
        }
    }
}

extern "C" void kernel_launch(void* const* d_in, const int* in_sizes, int n_in,
                              void* d_out, int out_size, void* d_ws, size_t ws_size,
                              hipStream_t stream) {
    const float* inputs = (const float*)d_in[0];
    const float* states = (const float*)d_in[1];
    const int*   ei     = (const int*)d_in[2];
    const float* W_ru   = (const float*)d_in[3];
    const float* b_ru   = (const float*)d_in[4];
    const float* W_c    = (const float*)d_in[5];
    const float* b_c    = (const float*)d_in[6];

    float* out  = (float*)d_out;
    float* out1 = out;                             /* x_bf early, new_state at end */
    float* out2 = out + (size_t)N_NODES * HID;     /* u, then new_state */

    char* ws = (char*)d_ws;
    int*            rs     = (int*)(ws + RS_OFF);
    unsigned short* csr    = (unsigned short*)(ws + CSR_OFF);
    int*            bsum   = (int*)(ws + BSUM_OFF);
    unsigned short* Wru_bf = (unsigned short*)(ws + WRU_OFF);
    unsigned short* Wc_bf  = (unsigned short*)(ws + WC_OFF);
    unsigned short* s_bf   = (unsigned short*)(ws + SBF_OFF);  /* then rs_bf */
    unsigned short* Ax     = (unsigned short*)(ws + AX_OFF);
    unsigned short* As     = (unsigned short*)(ws + AS_OFF);   /* then Ars */
    int*            counts = (int*)(ws + SBF_OFF);             /* dead before prep */
    unsigned short* x_bf   = (unsigned short*)d_out;           /* first 6.4MB of out1 */

    const int* src = ei;
    const int* dst = ei + N_EDGES;

    const int egrid      = (N_EDGES + 255) / 256;  /* 1563  */
    const int agg_grid   = N_NODES / 4;            /* 12500 */
    const int gemm_grid  = (N_NODES + 127) / 128;  /* 391   */
    const int prep_grid  = (N_NODES * HID / 4 + N_NODES * F_IN / 4) / 256;  /* 9375 */
    const int prepw_grid = (FIN * RU + FIN * HID) / 256;                    /* 288  */

    hipMemsetAsync(counts, 0, N_NODES * sizeof(int), stream);
    k_hist  <<<egrid, 256, 0, stream>>>(dst, counts);
    k_scan_a<<<NSCAN, 256, 0, stream>>>(counts, bsum);
    k_scan_b<<<1,     256, 0, stream>>>(bsum);
    k_scan_c<<<NSCAN, 256, 0, stream>>>(counts, bsum, rs);
    k_fill  <<<egrid, 256, 0, stream>>>(src, dst, rs, csr);
    k_prepW <<<prepw_grid, 256, 0, stream>>>(W_ru, W_c, Wru_bf, Wc_bf);
    k_prep  <<<prep_grid, 256, 0, stream>>>(states, inputs, (uint2*)s_bf, (uint2*)x_bf);
    k_agg1  <<<agg_grid, 256, 0, stream>>>(csr, rs, x_bf, (const unsigned*)s_bf,
                                           Ax, (unsigned*)As);
    k_gemm_ru<<<dim3(gemm_grid, 2), 256, 0, stream>>>(Ax, As, Wru_bf, b_ru, states,
                                                      s_bf /* rs_bf */, out2);
    k_agg2  <<<agg_grid, 256, 0, stream>>>(csr, rs, (const unsigned*)s_bf,
                                           (unsigned*)As /* Ars */);
    k_gemm_c<<<gemm_grid, 256, 0, stream>>>(Ax, As /* Ars */, Wc_bf, b_c, states,
                                            out2, out1, out2);
}

// Round 8
// 193.393 us; speedup vs baseline: 1.5205x; 1.2004x over previous
//
#include <hip/hip_runtime.h>
#include <hip/hip_bf16.h>
#include <math.h>

#define N_NODES 50000
#define N_EDGES 400000
#define F_IN    64
#define HID     128
#define FIN     192   /* F_IN + HID */
#define RU      256   /* 2*HID */

#define NSCAN   196   /* ceil(N_NODES/256) */

/* ---- ws layout (byte offsets), total ~33.2 MB ----
   rs     : int[N_NODES]          @ RS_OFF   CSR starts (mutated to ends by fill)
   csr    : ushort[N_EDGES]       @ CSR_OFF
   bsum   : int[256]              @ BSUM_OFF
   Wru_bf : bf16[RU][FIN]         @ WRU_OFF  (transposed W_ru)
   Wc_bf  : bf16[HID][FIN]        @ WC_OFF   (transposed W_c)
   s_bf   : bf16[N][HID]          @ SBF_OFF  prep -> agg1; THEN rs_bf (gemm_ru -> agg2).
                                             counts[] aliased pre-prep.
   Ax     : bf16[N][F_IN]         @ AX_OFF   agg1 -> gemm_ru, gemm_c
   As     : bf16[N][HID]          @ AS_OFF   agg1 -> gemm_ru; THEN Ars (agg2 -> gemm_c)
   x_bf   : bf16[N][F_IN]  lives in d_out[0:6.4MB] (dead before gemm_c writes out1) */
#define RS_OFF    0u
#define CSR_OFF   200064u
#define BSUM_OFF  1000064u
#define WRU_OFF   1001088u
#define WC_OFF    1099392u
#define SBF_OFF   1148544u
#define AX_OFF    13948544u
#define AS_OFF    20348544u

typedef __attribute__((ext_vector_type(8))) short short8;
typedef __attribute__((ext_vector_type(4))) float f32x4;

__device__ __forceinline__ float sigf(float x) { return 1.f / (1.f + expf(-x)); }
__device__ __forceinline__ float bf2f(unsigned short h) {
    return __uint_as_float(((unsigned)h) << 16);
}
__device__ __forceinline__ float bflo(unsigned v) { return __uint_as_float(v << 16); }
__device__ __forceinline__ float bfhi(unsigned v) { return __uint_as_float(v & 0xffff0000u); }
__device__ __forceinline__ unsigned short f2bf(float f) { /* RNE */
    unsigned u = __float_as_uint(f);
    return (unsigned short)((u + 0x7fff + ((u >> 16) & 1)) >> 16);
}
__device__ __forceinline__ unsigned packbf(float lo, float hi) {
    return ((unsigned)f2bf(hi) << 16) | (unsigned)f2bf(lo);
}

/* ---------------- CSR build ---------------- */
__global__ void k_hist(const int* __restrict__ dst, int* __restrict__ counts) {
    const int e = blockIdx.x * 256 + threadIdx.x;
    if (e < N_EDGES) atomicAdd(&counts[dst[e]], 1);
}

__device__ __forceinline__ int excl_scan_256(int v, int* tmp) {
    const int t = threadIdx.x;
    tmp[t] = v; __syncthreads();
    #pragma unroll
    for (int off = 1; off < 256; off <<= 1) {
        int u = (t >= off) ? tmp[t - off] : 0;
        __syncthreads();
        tmp[t] += u;
        __syncthreads();
    }
    return tmp[t] - v;
}

__global__ void k_scan_a(const int* __restrict__ counts, int* __restrict__ bsum) {
    __shared__ int tmp[256];
    const int i = blockIdx.x * 256 + threadIdx.x;
    const int v = (i < N_NODES) ? counts[i] : 0;
    excl_scan_256(v, tmp);
    if (threadIdx.x == 255) bsum[blockIdx.x] = tmp[255];
}

__global__ void k_scan_b(int* __restrict__ bsum) {
    __shared__ int tmp[256];
    const int t = threadIdx.x;
    const int v = (t < NSCAN) ? bsum[t] : 0;
    const int e = excl_scan_256(v, tmp);
    bsum[t] = e;
}

__global__ void k_scan_c(const int* __restrict__ counts, const int* __restrict__ bsum,
                         int* __restrict__ rs) {
    __shared__ int tmp[256];
    const int i = blockIdx.x * 256 + threadIdx.x;
    const int v = (i < N_NODES) ? counts[i] : 0;
    const int e = excl_scan_256(v, tmp);
    if (i < N_NODES) rs[i] = bsum[blockIdx.x] + e;
}

__global__ void k_fill(const int* __restrict__ src, const int* __restrict__ dst,
                       int* __restrict__ rs, unsigned short* __restrict__ csr) {
    const int e = blockIdx.x * 256 + threadIdx.x;
    if (e < N_EDGES) {
        const int pos = atomicAdd(&rs[dst[e]], 1);
        csr[pos] = (unsigned short)src[e];
    }
}

/* ------- prepW: transpose W to [col][k] and convert f32->bf16 ------- */
__global__ void k_prepW(const float* __restrict__ Wru, const float* __restrict__ Wc,
                        unsigned short* __restrict__ Wru_bf,
                        unsigned short* __restrict__ Wc_bf) {
    const int t = blockIdx.x * 256 + threadIdx.x;   /* 73728 threads exact */
    if (t < FIN * RU) {
        const int k = t >> 8, c = t & 255;
        Wru_bf[c * FIN + k] = f2bf(Wru[t]);
    } else {
        const int tt = t - FIN * RU;
        const int k = tt >> 7, c = tt & 127;
        Wc_bf[c * FIN + k] = f2bf(Wc[tt]);
    }
}

/* ------- prep: states -> s_bf, inputs -> x_bf (bf16 gather tables) ------- */
__global__ void k_prep(const float* __restrict__ states, const float* __restrict__ inputs,
                       uint2* __restrict__ s_bf2, uint2* __restrict__ x_bf2) {
    const int t = blockIdx.x * 256 + threadIdx.x;   /* 2.4M threads exact */
    if (t < N_NODES * HID / 4) {
        const float4 v = ((const float4*)states)[t];
        s_bf2[t] = make_uint2(packbf(v.x, v.y), packbf(v.z, v.w));
    } else {
        const int j = t - N_NODES * HID / 4;
        const float4 v = ((const float4*)inputs)[j];
        x_bf2[j] = make_uint2(packbf(v.x, v.y), packbf(v.z, v.w));
    }
}

/* ------- agg1: wave/node; edge-paired wide gathers of x,s; normalize; bf16 out ---
 * lanes 0-31 handle edge e, lanes 32-63 edge e+1; each lane loads uint (2 x-feats)
 * + uint2 (4 s-feats, 8B). 2 pairs per iteration -> 4 gathers in flight/lane.
 * __shfl_xor(...,32) combines the half-wave partials at the end.               */
__global__ __launch_bounds__(256) void k_agg1(
        const unsigned short* __restrict__ csr, const int* __restrict__ rs,
        const unsigned* __restrict__ x_u, const uint2* __restrict__ s_u2,
        unsigned* __restrict__ Ax_u, uint2* __restrict__ As_u2) {
    const int n = blockIdx.x * 4 + (threadIdx.x >> 6);
    const int lane = threadIdx.x & 63;
    const int half = lane >> 5;
    const int l = lane & 31;
    const int end   = rs[n];
    const int start = n ? rs[n - 1] : 0;
    float ax0 = 0.f, ax1 = 0.f, s0 = 0.f, s1 = 0.f, s2 = 0.f, s3 = 0.f;
    int e = start;
    for (; e + 4 <= end; e += 4) {
        const int ia = csr[e + half];
        const int ib = csr[e + 2 + half];
        const unsigned xa = x_u[(size_t)ia * 32 + l];
        const uint2    sa = s_u2[(size_t)ia * 32 + l];
        const unsigned xb = x_u[(size_t)ib * 32 + l];
        const uint2    sb = s_u2[(size_t)ib * 32 + l];
        ax0 += bflo(xa); ax1 += bfhi(xa);
        s0 += bflo(sa.x); s1 += bfhi(sa.x); s2 += bflo(sa.y); s3 += bfhi(sa.y);
        ax0 += bflo(xb); ax1 += bfhi(xb);
        s0 += bflo(sb.x); s1 += bfhi(sb.x); s2 += bflo(sb.y); s3 += bfhi(sb.y);
    }
    if (e + 2 <= end) {
        const int ia = csr[e + half];
        const unsigned xa = x_u[(size_t)ia * 32 + l];
        const uint2    sa = s_u2[(size_t)ia * 32 + l];
        ax0 += bflo(xa); ax1 += bfhi(xa);
        s0 += bflo(sa.x); s1 += bfhi(sa.x); s2 += bflo(sa.y); s3 += bfhi(sa.y);
        e += 2;
    }
    if (e < end && half == 0) {
        const int ia = csr[e];
        const unsigned xa = x_u[(size_t)ia * 32 + l];
        const uint2    sa = s_u2[(size_t)ia * 32 + l];
        ax0 += bflo(xa); ax1 += bfhi(xa);
        s0 += bflo(sa.x); s1 += bfhi(sa.x); s2 += bflo(sa.y); s3 += bfhi(sa.y);
    }
    ax0 += __shfl_xor(ax0, 32); ax1 += __shfl_xor(ax1, 32);
    s0  += __shfl_xor(s0, 32);  s1  += __shfl_xor(s1, 32);
    s2  += __shfl_xor(s2, 32);  s3  += __shfl_xor(s3, 32);
    if (half == 0) {
        const float inv = 1.f / fmaxf((float)(end - start), 1.f);
        Ax_u[(size_t)n * 32 + l]  = packbf(ax0 * inv, ax1 * inv);
        As_u2[(size_t)n * 32 + l] = make_uint2(packbf(s0 * inv, s1 * inv),
                                               packbf(s2 * inv, s3 * inv));
    }
}

/* ------- agg2: wave/node; edge-paired uint2 gathers of rs_bf; normalize ------- */
__global__ __launch_bounds__(256) void k_agg2(
        const unsigned short* __restrict__ csr, const int* __restrict__ rs,
        const uint2* __restrict__ rs_u2, uint2* __restrict__ Ars_u2) {
    const int n = blockIdx.x * 4 + (threadIdx.x >> 6);
    const int lane = threadIdx.x & 63;
    const int half = lane >> 5;
    const int l = lane & 31;
    const int end   = rs[n];
    const int start = n ? rs[n - 1] : 0;
    float a0 = 0.f, a1 = 0.f, a2 = 0.f, a3 = 0.f;
    int e = start;
    for (; e + 4 <= end; e += 4) {
        const int ia = csr[e + half];
        const int ib = csr[e + 2 + half];
        const uint2 va = rs_u2[(size_t)ia * 32 + l];
        const uint2 vb = rs_u2[(size_t)ib * 32 + l];
        a0 += bflo(va.x); a1 += bfhi(va.x); a2 += bflo(va.y); a3 += bfhi(va.y);
        a0 += bflo(vb.x); a1 += bfhi(vb.x); a2 += bflo(vb.y); a3 += bfhi(vb.y);
    }
    if (e + 2 <= end) {
        const int ia = csr[e + half];
        const uint2 va = rs_u2[(size_t)ia * 32 + l];
        a0 += bflo(va.x); a1 += bfhi(va.x); a2 += bflo(va.y); a3 += bfhi(va.y);
        e += 2;
    }
    if (e < end && half == 0) {
        const int ia = csr[e];
        const uint2 va = rs_u2[(size_t)ia * 32 + l];
        a0 += bflo(va.x); a1 += bfhi(va.x); a2 += bflo(va.y); a3 += bfhi(va.y);
    }
    a0 += __shfl_xor(a0, 32); a1 += __shfl_xor(a1, 32);
    a2 += __shfl_xor(a2, 32); a3 += __shfl_xor(a3, 32);
    if (half == 0) {
        const float inv = 1.f / fmaxf((float)(end - start), 1.f);
        Ars_u2[(size_t)n * 32 + l] = make_uint2(packbf(a0 * inv, a1 * inv),
                                                packbf(a2 * inv, a3 * inv));
    }
}

/* ------- GEMM 1 (MFMA): [Ax|As] @ Wru_bf -> sigmoid -> rs_bf / u -------
 * grid (391, 2): 128 rows x 128 cols per block; 4 waves, each owns TWO 16-row
 * stripes. A fragments load straight global->VGPR (line-coalesced); only Wt is
 * staged in LDS (51.2 KB -> 3 blocks/CU); each W ds_read feeds 2 MFMA.      */
__global__ __launch_bounds__(256, 3) void k_gemm_ru(
        const unsigned short* __restrict__ Ax, const unsigned short* __restrict__ As,
        const unsigned short* __restrict__ Wbf, const float* __restrict__ b,
        const float* __restrict__ states,
        unsigned short* __restrict__ rs_bf, float* __restrict__ u_out) {
    __shared__ unsigned short Wt[128][200];
    const int t  = threadIdx.x;
    const int n0 = blockIdx.x * 128;
    const int cb = blockIdx.y;            /* 0 -> r half (cols 0..127), 1 -> u half */

    #pragma unroll
    for (int it = 0; it < 12; ++it) {
        const int task = t + 256 * it;
        const int c = task / 24, g = task - c * 24;
        *(uint4*)(&Wt[c][g * 8]) =
            *(const uint4*)(Wbf + (size_t)(cb * 128 + c) * FIN + g * 8);
    }

    const int lane = t & 63, wave = t >> 6;
    const int fr = lane & 15;             /* frag row (A) / col (B) */
    const int fk = (lane >> 4) * 8;       /* frag k sub-offset      */

    short8 afr[2][6];
    const short8 zero = {};
    #pragma unroll
    for (int s = 0; s < 2; ++s) {
        const int n = n0 + wave * 32 + s * 16 + fr;
        if (n < N_NODES) {
            const unsigned short* axp = Ax + (size_t)n * F_IN + fk;
            const unsigned short* asp = As + (size_t)n * HID + fk;
            afr[s][0] = *(const short8*)(axp);
            afr[s][1] = *(const short8*)(axp + 32);
            afr[s][2] = *(const short8*)(asp);
            afr[s][3] = *(const short8*)(asp + 32);
            afr[s][4] = *(const short8*)(asp + 64);
            afr[s][5] = *(const short8*)(asp + 96);
        } else {
            #pragma unroll
            for (int j = 0; j < 6; ++j) afr[s][j] = zero;
        }
    }
    __syncthreads();

    f32x4 acc[2][8] = {};
    #pragma unroll
    for (int k0 = 0; k0 < 6; ++k0) {
        #pragma unroll
        for (int ct = 0; ct < 8; ++ct) {
            const short8 bw = *(const short8*)(&Wt[ct * 16 + fr][fk + k0 * 32]);
            acc[0][ct] = __builtin_amdgcn_mfma_f32_16x16x32_bf16(afr[0][k0], bw, acc[0][ct], 0, 0, 0);
            acc[1][ct] = __builtin_amdgcn_mfma_f32_16x16x32_bf16(afr[1][k0], bw, acc[1][ct], 0, 0, 0);
        }
    }

    #pragma unroll
    for (int s = 0; s < 2; ++s) {
        const int rbase = n0 + wave * 32 + s * 16 + (lane >> 4) * 4;
        #pragma unroll
        for (int ct = 0; ct < 8; ++ct) {
            const int colrel = ct * 16 + fr;
            const float bias = b[cb * 128 + colrel];
            #pragma unroll
            for (int i = 0; i < 4; ++i) {
                const int n = rbase + i;
                if (n < N_NODES) {
                    const float v = sigf(acc[s][ct][i] + bias);
                    const size_t idx = (size_t)n * HID + colrel;
                    if (cb == 0) {   /* r-gate: fuse r*states, store bf16 */
                        rs_bf[idx] = f2bf(v * states[idx]);
                    } else {
                        u_out[idx] = v;
                    }
                }
            }
        }
    }
}

/* ------- GEMM 2 (MFMA): [Ax|Ars] @ Wc_bf -> tanh -> gate -> new_state ------- */
__global__ __launch_bounds__(256, 3) void k_gemm_c(
        const unsigned short* __restrict__ Ax, const unsigned short* __restrict__ Ars,
        const unsigned short* __restrict__ Wbf, const float* __restrict__ b,
        const float* __restrict__ states, const float* __restrict__ u_in,
        float* __restrict__ out1, float* __restrict__ out2) {
    __shared__ unsigned short Wt[128][200];
    const int t  = threadIdx.x;
    const int n0 = blockIdx.x * 128;

    #pragma unroll
    for (int it = 0; it < 12; ++it) {
        const int task = t + 256 * it;
        const int c = task / 24, g = task - c * 24;
        *(uint4*)(&Wt[c][g * 8]) = *(const uint4*)(Wbf + (size_t)c * FIN + g * 8);
    }

    const int lane = t & 63, wave = t >> 6;
    const int fr = lane & 15;
    const int fk = (lane >> 4) * 8;

    short8 afr[2][6];
    const short8 zero = {};
    #pragma unroll
    for (int s = 0; s < 2; ++s) {
        const int n = n0 + wave * 32 + s * 16 + fr;
        if (n < N_NODES) {
            const unsigned short* axp = Ax  + (size_t)n * F_IN + fk;
            const unsigned short* arp = Ars + (size_t)n * HID + fk;
            afr[s][0] = *(const short8*)(axp);
            afr[s][1] = *(const short8*)(axp + 32);
            afr[s][2] = *(const short8*)(arp);
            afr[s][3] = *(const short8*)(arp + 32);
            afr[s][4] = *(const short8*)(arp + 64);
            afr[s][5] = *(const short8*)(arp + 96);
        } else {
            #pragma unroll
            for (int j = 0; j < 6; ++j) afr[s][j] = zero;
        }
    }
    __syncthreads();

    f32x4 acc[2][8] = {};
    #pragma unroll
    for (int k0 = 0; k0 < 6; ++k0) {
        #pragma unroll
        for (int ct = 0; ct < 8; ++ct) {
            const short8 bw = *(const short8*)(&Wt[ct * 16 + fr][fk + k0 * 32]);
            acc[0][ct] = __builtin_amdgcn_mfma_f32_16x16x32_bf16(afr[0][k0], bw, acc[0][ct], 0, 0, 0);
            acc[1][ct] = __builtin_amdgcn_mfma_f32_16x16x32_bf16(afr[1][k0], bw, acc[1][ct], 0, 0, 0);
        }
    }

    #pragma unroll
    for (int s = 0; s < 2; ++s) {
        const int rbase = n0 + wave * 32 + s * 16 + (lane >> 4) * 4;
        #pragma unroll
        for (int ct = 0; ct < 8; ++ct) {
            const int col = ct * 16 + fr;
            const float bias = b[col];
            #pragma unroll
            for (int i = 0; i < 4; ++i) {
                const int n = rbase + i;
                if (n < N_NODES) {
                    const size_t idx = (size_t)n * HID + col;
                    const float c  = tanhf(acc[s][ct][i] + bias);
                    const float uu = u_in[idx];
                    const float st = states[idx];
                    const float ns = uu * st + (1.f - uu) * c;
                    out1[idx] = ns;
                    out2[idx] = ns;
                }
            }
        }
    }
}

extern "C" void kernel_launch(void* const* d_in, const int* in_sizes, int n_in,
                              void* d_out, int out_size, void* d_ws, size_t ws_size,
                              hipStream_t stream) {
    const float* inputs = (const float*)d_in[0];
    const float* states = (const float*)d_in[1];
    const int*   ei     = (const int*)d_in[2];
    const float* W_ru   = (const float*)d_in[3];
    const float* b_ru   = (const float*)d_in[4];
    const float* W_c    = (const float*)d_in[5];
    const float* b_c    = (const float*)d_in[6];

    float* out  = (float*)d_out;
    float* out1 = out;                             /* x_bf early, new_state at end */
    float* out2 = out + (size_t)N_NODES * HID;     /* u, then new_state */

    char* ws = (char*)d_ws;
    int*            rs     = (int*)(ws + RS_OFF);
    unsigned short* csr    = (unsigned short*)(ws + CSR_OFF);
    int*            bsum   = (int*)(ws + BSUM_OFF);
    unsigned short* Wru_bf = (unsigned short*)(ws + WRU_OFF);
    unsigned short* Wc_bf  = (unsigned short*)(ws + WC_OFF);
    unsigned short* s_bf   = (unsigned short*)(ws + SBF_OFF);  /* then rs_bf */
    unsigned short* Ax     = (unsigned short*)(ws + AX_OFF);
    unsigned short* As     = (unsigned short*)(ws + AS_OFF);   /* then Ars */
    int*            counts = (int*)(ws + SBF_OFF);             /* dead before prep */
    unsigned short* x_bf   = (unsigned short*)d_out;           /* first 6.4MB of out1 */

    const int* src = ei;
    const int* dst = ei + N_EDGES;

    const int egrid      = (N_EDGES + 255) / 256;  /* 1563  */
    const int agg_grid   = N_NODES / 4;            /* 12500 */
    const int gemm_grid  = (N_NODES + 127) / 128;  /* 391   */
    const int prep_grid  = (N_NODES * HID / 4 + N_NODES * F_IN / 4) / 256;  /* 9375 */
    const int prepw_grid = (FIN * RU + FIN * HID) / 256;                    /* 288  */

    hipMemsetAsync(counts, 0, N_NODES * sizeof(int), stream);
    k_hist  <<<egrid, 256, 0, stream>>>(dst, counts);
    k_scan_a<<<NSCAN, 256, 0, stream>>>(counts, bsum);
    k_scan_b<<<1,     256, 0, stream>>>(bsum);
    k_scan_c<<<NSCAN, 256, 0, stream>>>(counts, bsum, rs);
    k_fill  <<<egrid, 256, 0, stream>>>(src, dst, rs, csr);
    k_prepW <<<prepw_grid, 256, 0, stream>>>(W_ru, W_c, Wru_bf, Wc_bf);
    k_prep  <<<prep_grid, 256, 0, stream>>>(states, inputs, (uint2*)s_bf, (uint2*)x_bf);
    k_agg1  <<<agg_grid, 256, 0, stream>>>(csr, rs, (const unsigned*)x_bf,
                                           (const uint2*)s_bf,
                                           (unsigned*)Ax, (uint2*)As);
    k_gemm_ru<<<dim3(gemm_grid, 2), 256, 0, stream>>>(Ax, As, Wru_bf, b_ru, states,
                                                      s_bf /* rs_bf */, out2);
    k_agg2  <<<agg_grid, 256, 0, stream>>>(csr, rs, (const uint2*)s_bf,
                                           (uint2*)As /* Ars */);
    k_gemm_c<<<gemm_grid, 256, 0, stream>>>(Ax, As /* Ars */, Wc_bf, b_c, states,
                                            out2, out1, out2);
}